// Round 2
// baseline (2745.543 us; speedup 1.0000x reference)
//
#include <hip/hip_runtime.h>
#include <cstdint>

#define HH   512
#define HD2  1024
#define HD3  1536
#define EE   300
#define VV   32000
#define BB   32
#define LLn  64
#define TT   32

typedef unsigned short u16;
typedef __attribute__((ext_vector_type(8))) short short8;
typedef __attribute__((ext_vector_type(4))) float f32x4;

__device__ __forceinline__ float fast_tanh(float x) {
    // tanh(x) = 1 - 2/(e^{2x}+1); handles +-inf correctly via __expf saturation
    float e = __expf(2.f * x);
    return 1.f - 2.f / (e + 1.f);
}
__device__ __forceinline__ float fast_sigmoid(float x) {
    float e = __expf(-x);
    return 1.f / (1.f + e);
}
__device__ __forceinline__ u16 f2bf(float x) {
    union { float f; unsigned u; } v; v.f = x;
    unsigned r = v.u + 0x7FFFu + ((v.u >> 16) & 1u);   // RNE
    return (u16)(r >> 16);
}

// ---------------------------------------------------------------------------
// Generic fp32 pre-GEMM: C[M x N] = A[M x K] @ W[K x N] + bias
// grid = (N/256, M/16), block = 256. Optional A-row gather (embedding lookup).
// ---------------------------------------------------------------------------
__global__ __launch_bounds__(256) void pre_gemm(
    const float* __restrict__ A, const float* __restrict__ W,
    const float* __restrict__ bias, float* __restrict__ C,
    int K, int N, const int* __restrict__ gather)
{
    __shared__ float a_lds[16 * 512];
    const int nt = blockIdx.x, mt = blockIdx.y, tid = threadIdx.x;
    const int col = nt * 256 + tid;

    float acc[16];
    const float bv = bias ? bias[col] : 0.f;
#pragma unroll
    for (int r = 0; r < 16; r++) acc[r] = bv;

    for (int kb = 0; kb < K; kb += 512) {
        const int klen = (K - kb < 512) ? (K - kb) : 512;
        const int row4 = klen >> 2;
        __syncthreads();
        for (int i = tid; i < 16 * row4; i += 256) {
            int r  = i / row4;
            int c4 = i - r * row4;
            int gr = mt * 16 + r;
            int src = gather ? gather[gr] : gr;
            float4 v = *(const float4*)(A + (size_t)src * K + kb + c4 * 4);
            *(float4*)(a_lds + r * klen + c4 * 4) = v;
        }
        __syncthreads();
        for (int k = 0; k < klen; k += 4) {
            const size_t wi = (size_t)(kb + k) * N + col;
            float w0 = W[wi];
            float w1 = W[wi + (size_t)N];
            float w2 = W[wi + (size_t)2 * N];
            float w3 = W[wi + (size_t)3 * N];
#pragma unroll
            for (int r = 0; r < 16; r++) {
                float4 a = *(const float4*)(a_lds + r * klen + k);
                acc[r] = fmaf(a.x, w0, acc[r]);
                acc[r] = fmaf(a.y, w1, acc[r]);
                acc[r] = fmaf(a.z, w2, acc[r]);
                acc[r] = fmaf(a.w, w3, acc[r]);
            }
        }
    }
#pragma unroll
    for (int r = 0; r < 16; r++)
        C[(size_t)(mt * 16 + r) * N + col] = acc[r];
}

// ---------------------------------------------------------------------------
// step_a: fused [finalize s_{t} from step t-1 partials] + [gemm1 of step t]
// grid = (6 col-tiles, 8 k-chunks of 64, 2 batch-halves), block = 256.
// ---------------------------------------------------------------------------
__global__ __launch_bounds__(256) void step_a(
    const float* __restrict__ parts2, const float* __restrict__ pst,
    const float* __restrict__ zb, const float* __restrict__ s_prev,
    const float* __restrict__ prev_s, float* __restrict__ s_cur,
    u16* __restrict__ sseq, const float* __restrict__ W_a,
    const float* __restrict__ W_hzr, float* __restrict__ parts1, int t)
{
    __shared__ float s_lds[64 * 16];   // [kk][b_local]
    const int jt = blockIdx.x, p = blockIdx.y, bh = blockIdx.z;
    const int tid = threadIdx.x;
    const int kk  = tid & 63, blq = tid >> 6;
    const int k0  = p * 64, b0 = bh * 16;

#pragma unroll
    for (int i = 0; i < 4; i++) {
        int bl = blq * 4 + i;
        int b  = b0 + bl;
        int h  = k0 + kk;
        float sv;
        if (t == 0) {
            sv = prev_s[b * HH + h];
        } else {
            float acc = pst[b * HH + h];
#pragma unroll
            for (int q = 0; q < 16; q++)
                acc += parts2[(q * BB + b) * HH + h];
            float st = fast_tanh(acc);
            float z  = zb[b * HH + h];
            float so = s_prev[b * HH + h];
            sv = fmaf(z, st - so, so);
        }
        s_lds[kk * 16 + bl] = sv;
        if (jt == 0) {
            s_cur[b * HH + h] = sv;
            if (t > 0)
                sseq[((size_t)b * TT + (t - 1)) * HH + h] = f2bf(sv);
        }
    }
    __syncthreads();

    const int j = jt * 256 + tid;
    const float* Wp; int ld;
    if (j < HH) { Wp = W_a + j;         ld = HH;  }
    else        { Wp = W_hzr + (j - HH); ld = HD2; }
    Wp += (size_t)k0 * ld;

    float acc[16];
#pragma unroll
    for (int r = 0; r < 16; r++) acc[r] = 0.f;
    for (int k = 0; k < 64; k++) {
        float w = Wp[(size_t)k * ld];
#pragma unroll
        for (int r = 0; r < 4; r++) {
            float4 s4 = *(const float4*)(s_lds + k * 16 + r * 4);
            acc[r * 4 + 0] = fmaf(s4.x, w, acc[r * 4 + 0]);
            acc[r * 4 + 1] = fmaf(s4.y, w, acc[r * 4 + 1]);
            acc[r * 4 + 2] = fmaf(s4.z, w, acc[r * 4 + 2]);
            acc[r * 4 + 3] = fmaf(s4.w, w, acc[r * 4 + 3]);
        }
    }
#pragma unroll
    for (int r = 0; r < 16; r++)
        parts1[((size_t)p * BB + b0 + r) * HD3 + j] = acc[r];
}

// ---------------------------------------------------------------------------
// step_attn: per-batch block. grid = 32, block = 256.
// ---------------------------------------------------------------------------
__global__ __launch_bounds__(256) void step_attn(
    const float* __restrict__ parts1, const float* __restrict__ Uh,
    const float* __restrict__ Gc, const float* __restrict__ Ge,
    const float* __restrict__ s_buf,
    const float* __restrict__ b_a, const float* __restrict__ v_w,
    const float* __restrict__ v_b, const float* __restrict__ b_hzr,
    const float* __restrict__ b_hs,
    float* __restrict__ rs, float* __restrict__ zb, float* __restrict__ pst,
    int t)
{
    const int b = blockIdx.x, tid = threadIdx.x;
    __shared__ float outs[HH];
    __shared__ float sc[256];
    __shared__ float attn[LLn];
    __shared__ float gcs[HD3];

    for (int h = tid; h < HH; h += 256) {
        float a = b_a[h];
#pragma unroll
        for (int p = 0; p < 8; p++)
            a += parts1[((size_t)p * BB + b) * HD3 + h];
        outs[h] = a;
    }
    __syncthreads();
    {
        const int l = tid & 63, jj = tid >> 6;
        const float* uh = Uh + ((size_t)b * LLn + l) * HH + jj * 128;
        const float* os = outs + jj * 128;
        const float* vw = v_w + jj * 128;
        float acc = 0.f;
        for (int h = 0; h < 128; h++)
            acc = fmaf(fast_tanh(os[h] + uh[h]), vw[h], acc);
        sc[tid] = acc;
    }
    __syncthreads();
    if (tid < 64) {
        float v = sc[tid] + sc[64 + tid] + sc[128 + tid] + sc[192 + tid] + v_b[0];
        float m = v;
        for (int o = 32; o > 0; o >>= 1) m = fmaxf(m, __shfl_xor(m, o));
        float e = __expf(v - m);
        float s = e;
        for (int o = 32; o > 0; o >>= 1) s += __shfl_xor(s, o);
        attn[tid] = e / s;
    }
    __syncthreads();
#pragma unroll
    for (int c = 0; c < 6; c++) {
        int j = c * 256 + tid;
        float acc = 0.f;
        for (int l = 0; l < LLn; l++)
            acc = fmaf(attn[l], Gc[((size_t)b * LLn + l) * HD3 + j], acc);
        gcs[j] = acc;
    }
    __syncthreads();
    const float* ge = Ge + (size_t)(b * TT + t) * HD3;
    for (int h = tid; h < HH; h += 256) {
        float gz = b_hzr[h] + ge[h] + gcs[h];
        float gr = b_hzr[HH + h] + ge[HH + h] + gcs[HH + h];
#pragma unroll
        for (int p = 0; p < 8; p++) {
            const float* pp = parts1 + ((size_t)p * BB + b) * HD3;
            gz += pp[HH + h];
            gr += pp[HD2 + h];
        }
        float z = fast_sigmoid(gz);
        float r = fast_sigmoid(gr);
        float sv = s_buf[b * HH + h];
        rs[b * HH + h]  = r * sv;
        zb[b * HH + h]  = z;
        pst[b * HH + h] = ge[HD2 + h] + gcs[HD2 + h] + b_hs[h];
    }
}

// ---------------------------------------------------------------------------
// step_gemm2: parts2[p][b][h] partials of (r*s) @ W_hid_s.
// grid = (2 col-tiles, 16 k-chunks of 32), block = 256.
// ---------------------------------------------------------------------------
__global__ __launch_bounds__(256) void step_gemm2(
    const float* __restrict__ rs, const float* __restrict__ W_hs,
    float* __restrict__ parts2)
{
    __shared__ float r_lds[32 * 32];   // [kk][b]
    const int ht = blockIdx.x, p = blockIdx.y, tid = threadIdx.x;
    const int k0 = p * 32;
    for (int i = tid; i < 1024; i += 256) {
        int b = i >> 5, kk = i & 31;
        r_lds[kk * 32 + b] = rs[b * HH + k0 + kk];
    }
    __syncthreads();
    const int h = ht * 256 + tid;
    float acc[32];
#pragma unroll
    for (int b = 0; b < 32; b++) acc[b] = 0.f;
    for (int kk = 0; kk < 32; kk++) {
        float w = W_hs[(size_t)(k0 + kk) * HH + h];
#pragma unroll
        for (int r = 0; r < 8; r++) {
            float4 s4 = *(const float4*)(r_lds + kk * 32 + r * 4);
            acc[r * 4 + 0] = fmaf(s4.x, w, acc[r * 4 + 0]);
            acc[r * 4 + 1] = fmaf(s4.y, w, acc[r * 4 + 1]);
            acc[r * 4 + 2] = fmaf(s4.z, w, acc[r * 4 + 2]);
            acc[r * 4 + 3] = fmaf(s4.w, w, acc[r * 4 + 3]);
        }
    }
#pragma unroll
    for (int b = 0; b < 32; b++)
        parts2[((size_t)p * BB + b) * HH + h] = acc[b];
}

// Finalize s_31 and write the last s_seq row. grid = 64, block = 256.
__global__ __launch_bounds__(256) void step_final_last(
    const float* __restrict__ parts2, const float* __restrict__ pst,
    const float* __restrict__ zb, const float* __restrict__ s_buf,
    u16* __restrict__ sseq)
{
    int idx = blockIdx.x * 256 + threadIdx.x;   // 16384
    int b = idx >> 9, h = idx & 511;
    float acc = pst[idx];
#pragma unroll
    for (int q = 0; q < 16; q++)
        acc += parts2[(q * BB + b) * HH + h];
    float st = fast_tanh(acc);
    float z = zb[idx], so = s_buf[idx];
    float sv = fmaf(z, st - so, so);
    sseq[((size_t)b * TT + (TT - 1)) * HH + h] = f2bf(sv);
}

// ---------------------------------------------------------------------------
// final_gemm: out[1024 x 32000] = s_seq(bf16) @ W_out + b_out via
// mfma_f32_16x16x32_bf16. Block tile 256(M) x 64(N), K staged 32 at a time.
// grid = (500, 4), block = 256 (4 waves; wave w owns m-tiles 4w..4w+3).
// ---------------------------------------------------------------------------
__global__ __launch_bounds__(256) void final_gemm(
    const u16* __restrict__ Abf, const float* __restrict__ Wout,
    const float* __restrict__ b_out, float* __restrict__ out)
{
    __shared__ u16 a_lds[256 * 40];   // row stride 40 (pad)
    __shared__ u16 b_lds[64 * 40];    // [n][k], stride 40
    const int nb = blockIdx.x, mb = blockIdx.y, tid = threadIdx.x;
    const int w = tid >> 6, ln = tid & 63;
    const int quad = ln >> 4, lm = ln & 15;
    const int n0 = nb * 64;

    f32x4 acc[4][4];
#pragma unroll
    for (int r = 0; r < 4; r++)
#pragma unroll
        for (int c = 0; c < 4; c++)
            acc[r][c] = (f32x4){0.f, 0.f, 0.f, 0.f};

    for (int kt = 0; kt < 16; kt++) {
        const int k0 = kt * 32;
        {   // stage A: one row-chunk (32 bf16 = 64 B = 4 x uint4) per thread
            const uint4* src = (const uint4*)(Abf + ((size_t)(mb * 256 + tid)) * HH + k0);
            uint4 v0 = src[0], v1 = src[1], v2 = src[2], v3 = src[3];
            uint4* dst = (uint4*)(a_lds + tid * 40);
            dst[0] = v0; dst[1] = v1; dst[2] = v2; dst[3] = v3;
        }
        {   // stage B: fp32 load (coalesced over n), convert, transpose into LDS
            int kr = tid >> 3, c8 = (tid & 7) * 8;
            const float4* wp = (const float4*)(Wout + (size_t)(k0 + kr) * VV + n0 + c8);
            float4 f0 = wp[0], f1 = wp[1];
            u16 u[8] = { f2bf(f0.x), f2bf(f0.y), f2bf(f0.z), f2bf(f0.w),
                         f2bf(f1.x), f2bf(f1.y), f2bf(f1.z), f2bf(f1.w) };
#pragma unroll
            for (int j = 0; j < 8; j++)
                b_lds[(c8 + j) * 40 + kr] = u[j];
        }
        __syncthreads();
        short8 af[4], bfr[4];
#pragma unroll
        for (int r = 0; r < 4; r++)
            af[r] = *(const short8*)(a_lds + ((w * 4 + r) * 16 + lm) * 40 + quad * 8);
#pragma unroll
        for (int c = 0; c < 4; c++)
            bfr[c] = *(const short8*)(b_lds + (c * 16 + lm) * 40 + quad * 8);
#pragma unroll
        for (int r = 0; r < 4; r++)
#pragma unroll
            for (int c = 0; c < 4; c++)
                acc[r][c] = __builtin_amdgcn_mfma_f32_16x16x32_bf16(
                    af[r], bfr[c], acc[r][c], 0, 0, 0);
        __syncthreads();
    }
#pragma unroll
    for (int r = 0; r < 4; r++) {
        int row = mb * 256 + (w * 4 + r) * 16 + quad * 4;
#pragma unroll
        for (int c = 0; c < 4; c++) {
            int col = n0 + c * 16 + lm;
            float bo = b_out[col];
#pragma unroll
            for (int q = 0; q < 4; q++)
                out[(size_t)(row + q) * VV + col] = acc[r][c][q] + bo;
        }
    }
}

// ---------------------------------------------------------------------------
extern "C" void kernel_launch(void* const* d_in, const int* in_sizes, int n_in,
                              void* d_out, int out_size, void* d_ws, size_t ws_size,
                              hipStream_t stream)
{
    const float* enc_h  = (const float*)d_in[0];
    const float* prev_s = (const float*)d_in[1];
    const int*   tw     = (const int*)  d_in[2];
    const float* embed  = (const float*)d_in[3];
    const float* W_a    = (const float*)d_in[4];
    const float* b_a    = (const float*)d_in[5];
    const float* U_a    = (const float*)d_in[6];
    const float* b_Ua   = (const float*)d_in[7];
    const float* v_w    = (const float*)d_in[8];
    const float* v_b    = (const float*)d_in[9];
    const float* W_emb  = (const float*)d_in[10];
    const float* b_emb  = (const float*)d_in[11];
    const float* W_hzr  = (const float*)d_in[12];
    const float* b_hzr  = (const float*)d_in[13];
    const float* W_hs   = (const float*)d_in[14];
    const float* b_hs   = (const float*)d_in[15];
    const float* W_ctx  = (const float*)d_in[16];
    const float* b_ctx  = (const float*)d_in[17];
    const float* W_out  = (const float*)d_in[18];
    const float* b_out  = (const float*)d_in[19];
    float* out = (float*)d_out;

    float* ws = (float*)d_ws;
    float* Uh     = ws;  ws += 2048 * 512;     // enc_h @ U_a + b_Ua
    float* Gc     = ws;  ws += 2048 * 1536;    // enc_h @ W_ctx + b_ctx
    float* Ge     = ws;  ws += 1024 * 1536;    // embed[tw] @ W_emb + b_emb
    float* parts1 = ws;  ws += 8 * 32 * 1536;  // k-chunk partials of s@[W_a|W_hzr]
    float* parts2 = ws;  ws += 16 * 32 * 512;  // k-chunk partials of rs@W_hs
    float* s0     = ws;  ws += 32 * 512;
    float* s1     = ws;  ws += 32 * 512;
    float* rs     = ws;  ws += 32 * 512;
    float* zb     = ws;  ws += 32 * 512;
    float* pst    = ws;  ws += 32 * 512;
    u16*   sseq   = (u16*)ws;                  // 1024 x 512 bf16

    // Loop-invariant precomputes
    pre_gemm<<<dim3(2, 128), 256, 0, stream>>>(enc_h, U_a,   b_Ua,  Uh, 1024, 512,  nullptr);
    pre_gemm<<<dim3(6, 128), 256, 0, stream>>>(enc_h, W_ctx, b_ctx, Gc, 1024, 1536, nullptr);
    pre_gemm<<<dim3(6, 64),  256, 0, stream>>>(embed, W_emb, b_emb, Ge, 300,  1536, tw);

    for (int t = 0; t < TT; t++) {
        float* s_cur  = (t & 1) ? s1 : s0;
        float* s_prev = (t & 1) ? s0 : s1;
        step_a<<<dim3(6, 8, 2), 256, 0, stream>>>(parts2, pst, zb, s_prev, prev_s,
                                                  s_cur, sseq, W_a, W_hzr, parts1, t);
        step_attn<<<dim3(32), 256, 0, stream>>>(parts1, Uh, Gc, Ge, s_cur,
                                                b_a, v_w, v_b, b_hzr, b_hs,
                                                rs, zb, pst, t);
        step_gemm2<<<dim3(2, 16), 256, 0, stream>>>(rs, W_hs, parts2);
    }
    step_final_last<<<dim3(64), 256, 0, stream>>>(parts2, pst, zb, s1, sseq);
    final_gemm<<<dim3(500, 4), 256, 0, stream>>>(sseq, W_out, b_out, out);
}